// Round 1
// baseline (1121.755 us; speedup 1.0000x reference)
//
#include <hip/hip_runtime.h>
#include <math.h>

#define B_ 8
#define T_ 12
#define N_ 500
#define D_ 64
#define K_ 20
#define M_ (B_*T_)              // 96
#define MND_ 3072000            // M_*N_*D_
#define NROWS_ 48000            // M_*N_

// workspace layout (float offsets)
#define XS_OFF  0ul                     // 3 stages x 2 mix x MND_
#define AGG_OFF (6ul*MND_)              // 4 x MND_
#define WC_OFF  (AGG_OFF + 4ul*MND_)    // 8*2*4096
#define WD_OFF  (WC_OFF + 65536ul)
#define BC_OFF  (WD_OFF + 65536ul)      // 8*2*64
#define BD_OFF  (BC_OFF + 1024ul)

using f4 = __attribute__((ext_vector_type(4))) float;

// ---------------- K1: fuse head-mixture weights ----------------
__global__ __launch_bounds__(256) void fuse_weights(
        const float* __restrict__ aw, const float* __restrict__ Bw,
        const float* __restrict__ ab, const float* __restrict__ Bb,
        float* __restrict__ wc, float* __restrict__ wd,
        float* __restrict__ bc, float* __restrict__ bd) {
    int e = blockIdx.x * 256 + threadIdx.x;
    if (e < 131072) {
        int dd = e & 4095; int l = (e >> 12) & 1; int r = (e >> 13) & 7; int cd = e >> 16;
        float s = 0.f;
        #pragma unroll
        for (int h = 0; h < 4; ++h)
            s += aw[((cd*8 + r)*4 + h)*2 + l] * Bw[(h*2 + l)*4096 + dd];
        (cd ? wd : wc)[(r*2 + l)*4096 + dd] = s;
    } else {
        int e2 = e - 131072;
        if (e2 < 2048) {
            int d = e2 & 63; int l = (e2 >> 6) & 1; int r = (e2 >> 7) & 7; int cd = e2 >> 10;
            float s = 0.f;
            #pragma unroll
            for (int h = 0; h < 4; ++h)
                s += ab[((cd*8 + r)*4 + h)*2 + l] * Bb[(h*2 + l)*64 + d];
            (cd ? bd : bc)[(r*2 + l)*64 + d] = s;
        }
    }
}

// ---------------- K2: [B,D,N,T] -> [M,N,D] transpose ----------------
__global__ __launch_bounds__(256) void transpose_in(
        const float* __restrict__ x0, const float* __restrict__ x1,
        float* __restrict__ xs) {
    int bid = blockIdx.x;
    int n = bid % N_; int b = (bid / N_) % B_; int i = bid / (N_ * B_);
    const float* __restrict__ x = i ? x1 : x0;
    float* __restrict__ xo = xs + (size_t)i * MND_;
    __shared__ float tile[64][13];
    #pragma unroll
    for (int q = 0; q < 3; ++q) {
        int e = q * 256 + threadIdx.x;       // 0..767
        int d = e / 12, t = e % 12;
        tile[d][t] = x[(((size_t)b * D_ + d) * N_ + n) * T_ + t];
    }
    __syncthreads();
    #pragma unroll
    for (int q = 0; q < 3; ++q) {
        int e = q * 256 + threadIdx.x;
        int t = e >> 6, d = e & 63;
        xo[(((size_t)b * T_ + t) * N_ + n) * D_ + d] = tile[d][t];
    }
}

// ---------------- K3: aggregation GEMM: O[mm,d] = sum_n adj[n,mm] * X[n,d] ----------------
// block: 128 threads, tile 128(mm) x 64(d), micro-tile 8x8
__global__ __launch_bounds__(128) void aggregate(
        const float* __restrict__ graphs, const float* __restrict__ xs_in,
        float* __restrict__ agg) {
    const int cmb = blockIdx.z;          // t*2 + j
    const int t = cmb >> 1, j = cmb & 1;
    const int m = blockIdx.y;
    const int mm0 = blockIdx.x * 128;
    const float* __restrict__ adj = graphs + (size_t)t * N_ * N_;
    const float* __restrict__ X = xs_in + (size_t)j * MND_ + (size_t)m * N_ * D_;
    float* __restrict__ O = agg + (size_t)cmb * MND_ + (size_t)m * N_ * D_;

    __shared__ float As[32][132];
    __shared__ float Xs[32][68];
    const int tid = threadIdx.x;
    const int ty = tid >> 3;     // 0..15 -> mm group ty*8
    const int tx = tid & 7;      // 0..7  -> d group tx*8
    float acc[8][8] = {};

    for (int n0 = 0; n0 < N_; n0 += 32) {
        #pragma unroll
        for (int q = 0; q < 32; ++q) {
            int e = q * 128 + tid;
            int kk = e >> 7, mml = e & 127;
            int n = n0 + kk, mm = mm0 + mml;
            As[kk][mml] = (n < N_ && mm < N_) ? adj[(size_t)n * N_ + mm] : 0.f;
        }
        #pragma unroll
        for (int q = 0; q < 16; ++q) {
            int e = q * 128 + tid;
            int kk = e >> 6, dd = e & 63;
            int n = n0 + kk;
            Xs[kk][dd] = (n < N_) ? X[(size_t)n * D_ + dd] : 0.f;
        }
        __syncthreads();
        for (int kk = 0; kk < 32; ++kk) {
            f4 a0 = *(const f4*)&As[kk][ty * 8];
            f4 a1 = *(const f4*)&As[kk][ty * 8 + 4];
            f4 x0 = *(const f4*)&Xs[kk][tx * 8];
            f4 x1 = *(const f4*)&Xs[kk][tx * 8 + 4];
            #pragma unroll
            for (int im = 0; im < 8; ++im) {
                float av = (im < 4) ? a0[im] : a1[im - 4];
                #pragma unroll
                for (int id = 0; id < 4; ++id) {
                    acc[im][id]     = fmaf(av, x0[id], acc[im][id]);
                    acc[im][id + 4] = fmaf(av, x1[id], acc[im][id + 4]);
                }
            }
        }
        __syncthreads();
    }
    #pragma unroll
    for (int im = 0; im < 8; ++im) {
        int mm = mm0 + ty * 8 + im;
        if (mm < N_) {
            f4 v0, v1;
            #pragma unroll
            for (int id = 0; id < 4; ++id) { v0[id] = acc[im][id]; v1[id] = acc[im][id + 4]; }
            *(f4*)&O[(size_t)mm * D_ + tx * 8] = v0;
            *(f4*)&O[(size_t)mm * D_ + tx * 8 + 4] = v1;
        }
    }
}

// ---------------- K4: combine: h[i] = sum_{t,j} relu(aggj@wc+bc) + tanh((aggj-aggi)@wd+bd) ----------------
// block: 256 threads, tile 64 rows x 64 d, micro-tile 4x4, weights via L1/L2
__global__ __launch_bounds__(256) void combine(
        const float* __restrict__ agg,
        const float* __restrict__ wc, const float* __restrict__ wd,
        const float* __restrict__ bcv, const float* __restrict__ bdv,
        float* __restrict__ xs_out, int l) {
    const int i = blockIdx.y;
    const int row0 = blockIdx.x * 64;
    const int tid = threadIdx.x;
    const int ty = tid >> 4;            // row quad
    const int tx = tid & 15;            // d quad
    const int d0 = tx * 4;
    const size_t rbase = (size_t)(row0 + ty * 4) * 64;
    float hacc[4][4] = {};

    for (int t = 0; t < 2; ++t) {
        #pragma unroll
        for (int j = 0; j < 2; ++j) {
            const int rel = (t * 2 + i) * 2 + j;
            const float* __restrict__ Wc = wc + (size_t)(rel * 2 + l) * 4096 + d0;
            const float* __restrict__ Aj = agg + (size_t)(t * 2 + j) * MND_ + rbase;
            f4 cacc[4];
            {
                f4 bv = *(const f4*)&bcv[(rel * 2 + l) * 64 + d0];
                #pragma unroll
                for (int r = 0; r < 4; ++r) cacc[r] = bv;
            }
            for (int k4 = 0; k4 < 16; ++k4) {
                f4 a[4], w[4];
                #pragma unroll
                for (int r = 0; r < 4; ++r) a[r] = *(const f4*)&Aj[(size_t)r * 64 + k4 * 4];
                #pragma unroll
                for (int kk = 0; kk < 4; ++kk) w[kk] = *(const f4*)&Wc[(size_t)(k4 * 4 + kk) * 64];
                #pragma unroll
                for (int r = 0; r < 4; ++r)
                    #pragma unroll
                    for (int kk = 0; kk < 4; ++kk)
                        cacc[r] += a[r][kk] * w[kk];
            }
            #pragma unroll
            for (int r = 0; r < 4; ++r)
                #pragma unroll
                for (int dd = 0; dd < 4; ++dd)
                    hacc[r][dd] += fmaxf(cacc[r][dd], 0.f);

            if (j != i) {
                const float* __restrict__ Wd = wd + (size_t)(rel * 2 + l) * 4096 + d0;
                const float* __restrict__ Ai = agg + (size_t)(t * 2 + i) * MND_ + rbase;
                f4 dacc[4];
                f4 bv = *(const f4*)&bdv[(rel * 2 + l) * 64 + d0];
                #pragma unroll
                for (int r = 0; r < 4; ++r) dacc[r] = bv;
                for (int k4 = 0; k4 < 16; ++k4) {
                    f4 aj[4], ai[4], w[4];
                    #pragma unroll
                    for (int r = 0; r < 4; ++r) aj[r] = *(const f4*)&Aj[(size_t)r * 64 + k4 * 4];
                    #pragma unroll
                    for (int r = 0; r < 4; ++r) ai[r] = *(const f4*)&Ai[(size_t)r * 64 + k4 * 4];
                    #pragma unroll
                    for (int kk = 0; kk < 4; ++kk) w[kk] = *(const f4*)&Wd[(size_t)(k4 * 4 + kk) * 64];
                    #pragma unroll
                    for (int r = 0; r < 4; ++r) {
                        f4 df = aj[r] - ai[r];
                        #pragma unroll
                        for (int kk = 0; kk < 4; ++kk)
                            dacc[r] += df[kk] * w[kk];
                    }
                }
                #pragma unroll
                for (int r = 0; r < 4; ++r)
                    #pragma unroll
                    for (int dd = 0; dd < 4; ++dd)
                        hacc[r][dd] += tanhf(dacc[r][dd]);
            } else {
                f4 bv = *(const f4*)&bdv[(rel * 2 + l) * 64 + d0];
                float tb[4];
                #pragma unroll
                for (int dd = 0; dd < 4; ++dd) tb[dd] = tanhf(bv[dd]);
                #pragma unroll
                for (int r = 0; r < 4; ++r)
                    #pragma unroll
                    for (int dd = 0; dd < 4; ++dd)
                        hacc[r][dd] += tb[dd];
            }
        }
    }
    float* __restrict__ Ho = xs_out + (size_t)i * MND_ + rbase + d0;
    #pragma unroll
    for (int r = 0; r < 4; ++r) {
        f4 v;
        #pragma unroll
        for (int dd = 0; dd < 4; ++dd) v[dd] = hacc[r][dd];
        *(f4*)&Ho[(size_t)r * 64] = v;
    }
}

// ---------------- K5: summarize: weighted K-neighbor gather + transpose to [b,c,n,t] ----------------
// block: 192 threads (c = l*64+d), 8 nodes x 12 tt staged in LDS
__global__ __launch_bounds__(192) void summarize(
        const float* __restrict__ XS, const int* __restrict__ nbr,
        const float* __restrict__ nw, float* __restrict__ out) {
    int bid = blockIdx.x;
    int tile = bid % 63;
    int t = (bid / 63) & 1;
    int b = (bid / 126) & 7;
    int i = bid / 1008;
    int n0 = tile * 8;
    int tid = threadIdx.x;
    int l = tid >> 6, d = tid & 63;

    __shared__ int   nb_s[8][20];
    __shared__ float w_s[8][20];
    __shared__ float staged[96][193];

    if (tid < 160) {
        int nn = tid / 20, k = tid % 20;
        int n = n0 + nn;
        nb_s[nn][k] = (n < N_) ? nbr[((size_t)t * N_ + n) * K_ + k] : 0;
        w_s[nn][k]  = (n < N_) ? nw[((size_t)t * N_ + n) * K_ + k] : 0.f;
    }
    __syncthreads();

    const float* __restrict__ Xbase = XS + ((size_t)l * 2 + i) * MND_ + (size_t)b * T_ * N_ * D_ + d;
    for (int p = 0; p < 96; ++p) {
        int nn = p / 12, tt = p % 12;
        if (n0 + nn >= N_) break;
        const float* __restrict__ Xm = Xbase + (size_t)tt * N_ * D_;
        float acc = 0.f;
        #pragma unroll
        for (int k = 0; k < K_; ++k)
            acc = fmaf(Xm[(size_t)nb_s[nn][k] * D_], w_s[nn][k], acc);
        staged[p][tid] = acc;
    }
    __syncthreads();

    size_t obase = ((size_t)(i * 8 + b) * 384 + (size_t)t * 192) * 6000 + (size_t)n0 * 12;
    int plim = (N_ - n0) * 12; if (plim > 96) plim = 96;
    for (int it = 0; it < 96; ++it) {
        int e = it * 192 + tid;
        int c2 = e / 96, p = e % 96;
        if (p < plim) out[obase + (size_t)c2 * 6000 + p] = staged[p][c2];
    }
}

extern "C" void kernel_launch(void* const* d_in, const int* in_sizes, int n_in,
                              void* d_out, int out_size, void* d_ws, size_t ws_size,
                              hipStream_t stream) {
    const float* x0     = (const float*)d_in[0];
    const float* x1     = (const float*)d_in[1];
    const float* graphs = (const float*)d_in[2];
    const int*   nbr    = (const int*)d_in[3];
    const float* nwt    = (const float*)d_in[4];
    const float* aw     = (const float*)d_in[5];
    const float* Bw     = (const float*)d_in[6];
    const float* ab     = (const float*)d_in[7];
    const float* Bb     = (const float*)d_in[8];
    float* out = (float*)d_out;
    float* ws  = (float*)d_ws;

    float* XS  = ws + XS_OFF;
    float* AGG = ws + AGG_OFF;
    float* WC  = ws + WC_OFF;
    float* WD  = ws + WD_OFF;
    float* BC  = ws + BC_OFF;
    float* BD  = ws + BD_OFF;

    fuse_weights<<<520, 256, 0, stream>>>(aw, Bw, ab, Bb, WC, WD, BC, BD);
    transpose_in<<<8000, 256, 0, stream>>>(x0, x1, XS);
    for (int l = 0; l < 2; ++l) {
        aggregate<<<dim3(4, 96, 4), 128, 0, stream>>>(graphs, XS + (size_t)l * 2 * MND_, AGG);
        combine<<<dim3(750, 2), 256, 0, stream>>>(AGG, WC, WD, BC, BD,
                                                  XS + (size_t)(l + 1) * 2 * MND_, l);
    }
    summarize<<<2016, 192, 0, stream>>>(XS, nbr, nwt, out);
}